// Round 1
// baseline (9503.327 us; speedup 1.0000x reference)
//
#include <hip/hip_runtime.h>
#include <hip/hip_fp16.h>

// IGIRNN: gate_x = x@Wx^T+bx (recomputed in-loop); scan: gate_h=h@Wh^T+bh,
// rg=sig(i_r), ig=sig(i_i), ng=tanh(rg*gate_h), h'=ng+ig*(h-ng); out=h_T@Wfc^T+bfc.
//
// Design: persistent cooperative kernel, 256 blocks x 256 thr (1/CU, 4 waves).
//  - 8 row-groups (16 batch rows) x 32 col-WGs (32 h-cols). Groups independent.
//  - Wh slice [32][1024] + Wx slice [64][256] live in LDS whole kernel (f16, padded).
//  - Per step: stage h (f16, 32KB) + x_t (f32->f16) to LDS; 16x16x32 f16 MFMA;
//    waves 0,1 = (ntile, khalf0), waves 2,3 = khalf1 -> LDS reduce; pointwise in f32
//    with f32 master h in registers; write h' f16 to double-buffered global.
//  - Per-group flag barrier: syncthreads (drains stores to L2) -> tid0 release-store
//    stamp (wbl2 flushes L2 dirty to LLC) -> wave0 relaxed-polls 32 flags ->
//    acquire fence (inv) -> syncthreads.

#define BB 128
#define TT 1024
#define ID 256
#define HH 1024

using f16   = _Float16;
using f16x8 = __attribute__((ext_vector_type(8))) _Float16;
using f32x4 = __attribute__((ext_vector_type(4))) float;

// LDS layout (bytes). Row pads chosen so ds_read_b128 rows land on rotating banks.
#define LDH 1032   // f16 elems/row for h_lds, wh_lds (stride 2064 B -> bank +4/row)
#define LDX 264    // f16 elems/row for x_lds, wx_lds (stride 528 B  -> bank +4/row)
#define OFF_H    0                    // h_lds  [16][LDH] f16 = 33024
#define OFF_WH   33024                // wh_lds [32][LDH] f16 = 66048
#define OFF_WX   99072                // wx_lds [64][LDX] f16 = 33792
#define OFF_X    132864               // x_lds  [16][LDX] f16 = 8448
#define OFF_XCHG 141312               // xchg   [4][16][17] f32 = 4352
#define LDS_SIZE 145664

__device__ __forceinline__ void store4h(f16* dst, float a, float b, float c, float d) {
  union { f16 h[4]; unsigned long long u; } p;
  p.h[0] = (f16)a; p.h[1] = (f16)b; p.h[2] = (f16)c; p.h[3] = (f16)d;
  *reinterpret_cast<unsigned long long*>(dst) = p.u;
}

__global__ __launch_bounds__(256, 1) void rnn_core(
    const float* __restrict__ x, const float* __restrict__ Wx, const float* __restrict__ bx,
    const float* __restrict__ Wh, const float* __restrict__ bh,
    f16* __restrict__ hbuf,      // [2][128][1024] f16, double-buffered state
    float* __restrict__ hfin,    // [128][1024] f32, final state for FC
    int* __restrict__ flags)     // [8][32] stamps, 64B-strided (16 ints)
{
  extern __shared__ char lds[];
  f16*  h_lds  = (f16*)(lds + OFF_H);
  f16*  wh_lds = (f16*)(lds + OFF_WH);
  f16*  wx_lds = (f16*)(lds + OFF_WX);
  f16*  x_lds  = (f16*)(lds + OFF_X);
  float* xchg  = (float*)(lds + OFF_XCHG);

  const int tid  = threadIdx.x;
  const int lane = tid & 63;
  const int w    = tid >> 6;            // wave 0..3
  const int g    = blockIdx.x & 7;      // row group (maps to XCD under %8 round-robin)
  const int cw   = blockIdx.x >> 3;     // column WG 0..31
  const int b0   = g * 16;
  const int j0   = cw * 32;

  // ---- one-time weight staging (f32 global -> f16 LDS) ----
  for (int c = tid; c < 8192; c += 256) {            // Wh rows j0..j0+31
    int row = c >> 8, k4 = c & 255;
    float4 v = *reinterpret_cast<const float4*>(Wh + (size_t)(j0 + row) * HH + k4 * 4);
    store4h(wh_lds + row * LDH + k4 * 4, v.x, v.y, v.z, v.w);
  }
  for (int c = tid; c < 4096; c += 256) {            // Wx rows: i_r j0..+31, i_i 1024+j0..+31
    int row = c >> 6, k4 = c & 63;
    int gr = (row < 32) ? (j0 + row) : (HH + j0 + row - 32);
    float4 v = *reinterpret_cast<const float4*>(Wx + (size_t)gr * ID + k4 * 4);
    store4h(wx_lds + row * LDX + k4 * 4, v.x, v.y, v.z, v.w);
  }

  // per-lane constants; C/D layout: col = lane&15, row = (lane>>4)*4 + reg
  const int col  = lane & 15;
  const int row4 = (lane >> 4) * 4;
  const int jc   = j0 + (w & 1) * 16 + col;          // output column (waves 0,1)
  float bh_r = 0.f, bxr_r = 0.f, bxi_r = 0.f;
  if (w < 2) { bh_r = bh[jc]; bxr_r = bx[jc]; bxi_r = bx[HH + jc]; }

  float hm0 = 0.f, hm1 = 0.f, hm2 = 0.f, hm3 = 0.f;  // f32 master h (waves 0,1)

  // ---- init h0 = 0 in hbuf[0], then group barrier (stamp 1) ----
  if (w < 2) {
    #pragma unroll
    for (int r = 0; r < 4; ++r)
      hbuf[(size_t)(b0 + row4 + r) * HH + jc] = (f16)0.f;
  }
  __syncthreads();
  int* myflag = flags + (g * 32 + cw) * 16;
  if (tid == 0) __hip_atomic_store(myflag, 1, __ATOMIC_RELEASE, __HIP_MEMORY_SCOPE_AGENT);
  if (w == 0) {
    int v;
    do { v = __hip_atomic_load(flags + (g * 32 + (lane & 31)) * 16,
                               __ATOMIC_RELAXED, __HIP_MEMORY_SCOPE_AGENT);
    } while (!__all(v >= 1));
    __builtin_amdgcn_fence(__ATOMIC_ACQUIRE, "agent");
  }
  __syncthreads();

  for (int t = 0; t < TT; ++t) {
    // ---- stage h(t) rows b0..b0+15 (f16, 32KB) ----
    const f16* hsrc = hbuf + (size_t)(t & 1) * (BB * HH) + (size_t)b0 * HH;
    #pragma unroll
    for (int it = 0; it < 8; ++it) {
      int c = tid + it * 256;
      int row = c >> 7, k8 = c & 127;
      ulonglong2 v = *reinterpret_cast<const ulonglong2*>(hsrc + row * HH + k8 * 8);
      *reinterpret_cast<ulonglong2*>(h_lds + row * LDH + k8 * 8) = v;
    }
    // ---- stage x_t (f32 -> f16) ----
    #pragma unroll
    for (int it = 0; it < 4; ++it) {
      int c = tid + it * 256;
      int row = c >> 6, k4 = c & 63;
      float4 v = *reinterpret_cast<const float4*>(
          x + ((size_t)(b0 + row) * TT + t) * ID + k4 * 4);
      store4h(x_lds + row * LDX + k4 * 4, v.x, v.y, v.z, v.w);
    }
    __syncthreads();

    // ---- gate_h: wave w -> ntile = w&1 (16 cols), khalf = w>>1 (K=512) ----
    f32x4 gh = {0.f, 0.f, 0.f, 0.f};
    {
      const f16* pa = h_lds + (lane & 15) * LDH + (lane >> 4) * 8 + (w >> 1) * 512;
      const f16* pb = wh_lds + ((w & 1) * 16 + (lane & 15)) * LDH + (lane >> 4) * 8 + (w >> 1) * 512;
      #pragma unroll
      for (int ks = 0; ks < 16; ++ks) {
        f16x8 a = *reinterpret_cast<const f16x8*>(pa + ks * 32);
        f16x8 b = *reinterpret_cast<const f16x8*>(pb + ks * 32);
        gh = __builtin_amdgcn_mfma_f32_16x16x32_f16(a, b, gh, 0, 0, 0);
      }
    }
    // ---- gate_x: wave w -> gate = w>>1 (0=i_r,1=i_i), ntile = w&1; K=256 ----
    f32x4 gx = {0.f, 0.f, 0.f, 0.f};
    {
      const f16* pa = x_lds + (lane & 15) * LDX + (lane >> 4) * 8;
      const f16* pb = wx_lds + ((w >> 1) * 32 + (w & 1) * 16 + (lane & 15)) * LDX + (lane >> 4) * 8;
      #pragma unroll
      for (int ks = 0; ks < 8; ++ks) {
        f16x8 a = *reinterpret_cast<const f16x8*>(pa + ks * 32);
        f16x8 b = *reinterpret_cast<const f16x8*>(pb + ks * 32);
        gx = __builtin_amdgcn_mfma_f32_16x16x32_f16(a, b, gx, 0, 0, 0);
      }
    }

    // ---- cross-wave exchange: waves 2,3 export gh partial (khalf1) + i_i ----
    if (w >= 2) {
      float* dgh = xchg + (w & 1) * 272;        // 16*17
      float* dgx = xchg + (2 + (w & 1)) * 272;
      #pragma unroll
      for (int r = 0; r < 4; ++r) {
        dgh[(row4 + r) * 17 + col] = gh[r];
        dgx[(row4 + r) * 17 + col] = gx[r];
      }
    }
    __syncthreads();

    // ---- pointwise GRU update (waves 0,1), f32 master h in regs ----
    if (w < 2) {
      const float* sgh = xchg + w * 272;
      const float* sgx = xchg + (2 + w) * 272;
      f16* hdst = hbuf + (size_t)((t + 1) & 1) * (BB * HH);
      float hmv[4] = {hm0, hm1, hm2, hm3};
      float hn[4];
      #pragma unroll
      for (int r = 0; r < 4; ++r) {
        float ghf = gh[r] + sgh[(row4 + r) * 17 + col] + bh_r;
        float ir  = gx[r] + bxr_r;
        float ii  = sgx[(row4 + r) * 17 + col] + bxi_r;
        float rg  = 1.f / (1.f + __expf(-ir));
        float ig  = 1.f / (1.f + __expf(-ii));
        float z   = rg * ghf;
        z = fminf(fmaxf(z, -15.f), 15.f);     // avoid inf-inf NaN in tanh
        float e   = __expf(-2.f * z);
        float ng  = (1.f - e) / (1.f + e);
        float h_  = ng + ig * (hmv[r] - ng);
        hn[r] = h_;
        hdst[(size_t)(b0 + row4 + r) * HH + jc] = (f16)h_;
      }
      hm0 = hn[0]; hm1 = hn[1]; hm2 = hn[2]; hm3 = hn[3];
    }
    __syncthreads();   // drains all waves' h' stores into L2 (vmcnt(0) before s_barrier)

    // ---- per-group barrier, stamp t+2 ----
    int stamp = t + 2;
    if (tid == 0) __hip_atomic_store(myflag, stamp, __ATOMIC_RELEASE, __HIP_MEMORY_SCOPE_AGENT);
    if (w == 0) {
      int v;
      do { v = __hip_atomic_load(flags + (g * 32 + (lane & 31)) * 16,
                                 __ATOMIC_RELAXED, __HIP_MEMORY_SCOPE_AGENT);
      } while (!__all(v >= stamp));
      __builtin_amdgcn_fence(__ATOMIC_ACQUIRE, "agent");
    }
    __syncthreads();
  }

  // ---- export final h in f32 for the FC epilogue ----
  if (w < 2) {
    float hmv[4] = {hm0, hm1, hm2, hm3};
    #pragma unroll
    for (int r = 0; r < 4; ++r)
      hfin[(size_t)(b0 + row4 + r) * HH + jc] = hmv[r];
  }
}

// out[b][o] = sum_k hfin[b][k] * Wfc[o][k] + bfc[o];  128x256, K=1024.
__global__ __launch_bounds__(64) void fc_kernel(
    const float* __restrict__ hfin, const float* __restrict__ Wfc,
    const float* __restrict__ bfc, float* __restrict__ out)
{
  const int lane = threadIdx.x;
  const int mb = blockIdx.x >> 4, nb = blockIdx.x & 15;
  const int col = lane & 15, row4 = (lane >> 4) * 4;
  const float* pa = hfin + (size_t)(mb * 16 + (lane & 15)) * HH + (lane >> 4) * 8;
  const float* pb = Wfc  + (size_t)(nb * 16 + (lane & 15)) * HH + (lane >> 4) * 8;
  f32x4 acc = {0.f, 0.f, 0.f, 0.f};
  for (int kc = 0; kc < 32; ++kc) {
    f16x8 a, b;
    #pragma unroll
    for (int e = 0; e < 8; ++e) {
      a[e] = (f16)pa[kc * 32 + e];
      b[e] = (f16)pb[kc * 32 + e];
    }
    acc = __builtin_amdgcn_mfma_f32_16x16x32_f16(a, b, acc, 0, 0, 0);
  }
  float bias = bfc[nb * 16 + col];
  #pragma unroll
  for (int r = 0; r < 4; ++r)
    out[(size_t)(mb * 16 + row4 + r) * 256 + nb * 16 + col] = acc[r] + bias;
}

extern "C" void kernel_launch(void* const* d_in, const int* in_sizes, int n_in,
                              void* d_out, int out_size, void* d_ws, size_t ws_size,
                              hipStream_t stream) {
  const float* x   = (const float*)d_in[0];
  const float* Wx  = (const float*)d_in[1];
  const float* bx  = (const float*)d_in[2];
  const float* Wh  = (const float*)d_in[3];
  const float* bh  = (const float*)d_in[4];
  const float* Wfc = (const float*)d_in[5];
  const float* bfc = (const float*)d_in[6];
  float* out = (float*)d_out;

  char* ws = (char*)d_ws;
  f16*   hbuf  = (f16*)ws;                 // 2*128*1024*2  = 524288 B
  float* hfin  = (float*)(ws + 524288);    // 128*1024*4    = 524288 B
  int*   flags = (int*)(ws + 1048576);     // 8*32*16*4     = 16384 B

  hipMemsetAsync(flags, 0, 16384, stream);

  (void)hipFuncSetAttribute((const void*)rnn_core,
                            hipFuncAttributeMaxDynamicSharedMemorySize, LDS_SIZE);

  void* args[8];
  args[0] = (void*)&x;    args[1] = (void*)&Wx;   args[2] = (void*)&bx;
  args[3] = (void*)&Wh;   args[4] = (void*)&bh;   args[5] = (void*)&hbuf;
  args[6] = (void*)&hfin; args[7] = (void*)&flags;
  hipError_t err = hipLaunchCooperativeKernel((void*)rnn_core, dim3(256), dim3(256),
                                              args, LDS_SIZE, stream);
  if (err != hipSuccess) {
    // co-residency still holds by construction (256 blocks, 1/CU, exclusive GPU)
    rnn_core<<<dim3(256), dim3(256), LDS_SIZE, stream>>>(x, Wx, bx, Wh, bh, hbuf, hfin, flags);
  }

  fc_kernel<<<dim3(128), dim3(64), 0, stream>>>(hfin, Wfc, bfc, out);
}

// Round 2
// 6489.739 us; speedup vs baseline: 1.4644x; 1.4644x over previous
//
#include <hip/hip_runtime.h>
#include <hip/hip_fp16.h>

// IGIRNN persistent-scan kernel, round 2.
// Round-1 bottleneck: per-step agent RELEASE/ACQUIRE fences (buffer_wbl2 +
// buffer_inv = full L2 maintenance per WG per step) -> 22K cyc/step, all
// pipes idle. Round 2: cross-WG h exchange + flags via cache-bypassing
// relaxed SYSTEM-scope atomics (LLC-coherent, no L2 flush). Writer ordering
// via explicit s_waitcnt vmcnt(0) before flag store (write-through data
// needs no wbl2). gate_x MFMA + x staging (plain cached loads, read-only
// data) hoisted BEFORE the poll to overlap writer latency.
//
// Decomposition: 256 WGs x 256 thr (1/CU). 8 row-groups (16 batch rows) x
// 32 col-WGs (32 h cols). Wh/Wx slices persistent in LDS (f16). f32 master
// h in registers; f16 h only as MFMA transport via LLC.

#define BB 128
#define TT 1024
#define ID 256
#define HH 1024

using f16   = _Float16;
using f16x8 = __attribute__((ext_vector_type(8))) _Float16;
using f32x4 = __attribute__((ext_vector_type(4))) float;
typedef unsigned long long u64;

// LDS layout (f16 elems / bytes)
#define LDH 1032   // h_lds, wh_lds row stride (2064 B -> bank +4/row)
#define LDX 264    // x_lds, wx_lds row stride
#define LDS_HS 40  // hstage row stride (80 B)
#define OFF_H    0                    // h_lds  [16][LDH]  = 33024 B
#define OFF_WH   33024                // wh_lds [32][LDH]  = 66048 B
#define OFF_WX   99072                // wx_lds [64][LDX]  = 33792 B
#define OFF_X    132864               // x_lds  [16][LDX]  = 8448 B
#define OFF_XCHG 141312               // xchg   [4][16][17] f32 = 4352 B
#define OFF_HS   145664               // hstage [16][LDS_HS] f16 = 1280 B
#define LDS_SIZE 146944

__device__ __forceinline__ void store4h(f16* dst, float a, float b, float c, float d) {
  union { f16 h[4]; u64 u; } p;
  p.h[0] = (f16)a; p.h[1] = (f16)b; p.h[2] = (f16)c; p.h[3] = (f16)d;
  *reinterpret_cast<u64*>(dst) = p.u;
}

__global__ __launch_bounds__(256, 1) void rnn_core(
    const float* __restrict__ x, const float* __restrict__ Wx, const float* __restrict__ bx,
    const float* __restrict__ Wh, const float* __restrict__ bh,
    f16* __restrict__ hbuf,      // [2][128][1024] f16 (LLC-coherent exchange)
    float* __restrict__ hfin,    // [128][1024] f32 final state
    int* __restrict__ flags)     // [8][32] stamps, 64B-strided
{
  extern __shared__ char lds[];
  f16*  h_lds  = (f16*)(lds + OFF_H);
  f16*  wh_lds = (f16*)(lds + OFF_WH);
  f16*  wx_lds = (f16*)(lds + OFF_WX);
  f16*  x_lds  = (f16*)(lds + OFF_X);
  float* xchg  = (float*)(lds + OFF_XCHG);
  f16*  hstage = (f16*)(lds + OFF_HS);

  const int tid  = threadIdx.x;
  const int lane = tid & 63;
  const int w    = tid >> 6;            // wave 0..3
  const int g    = blockIdx.x & 7;      // row group
  const int cw   = blockIdx.x >> 3;     // column WG 0..31
  const int b0   = g * 16;
  const int j0   = cw * 32;

  // ---- one-time weight staging (f32 global -> f16 LDS) ----
  for (int c = tid; c < 8192; c += 256) {            // Wh rows j0..j0+31
    int row = c >> 8, k4 = c & 255;
    float4 v = *reinterpret_cast<const float4*>(Wh + (size_t)(j0 + row) * HH + k4 * 4);
    store4h(wh_lds + row * LDH + k4 * 4, v.x, v.y, v.z, v.w);
  }
  for (int c = tid; c < 4096; c += 256) {            // Wx rows: i_r j0..+31, i_i 1024+j0..+31
    int row = c >> 6, k4 = c & 63;
    int gr = (row < 32) ? (j0 + row) : (HH + j0 + row - 32);
    float4 v = *reinterpret_cast<const float4*>(Wx + (size_t)gr * ID + k4 * 4);
    store4h(wx_lds + row * LDX + k4 * 4, v.x, v.y, v.z, v.w);
  }

  // C/D layout: col = lane&15, row = (lane>>4)*4 + reg
  const int col  = lane & 15;
  const int row4 = (lane >> 4) * 4;
  const int jc   = j0 + (w & 1) * 16 + col;          // output column (waves 0,1)
  float bh_r = 0.f, bxr_r = 0.f, bxi_r = 0.f;
  if (w < 2) { bh_r = bh[jc]; bxr_r = bx[jc]; bxi_r = bx[HH + jc]; }

  float hm0 = 0.f, hm1 = 0.f, hm2 = 0.f, hm3 = 0.f;  // f32 master h (waves 0,1)

  int* myflag = flags + (g * 32 + cw) * 16;
  const int* pollflag = flags + (g * 32 + (lane & 31)) * 16;

  __syncthreads();   // weights staged

  for (int t = 0; t < TT; ++t) {
    // ---- A: stage x_t (plain cached loads; read-only => L2 reuse is safe) ----
    #pragma unroll
    for (int it = 0; it < 4; ++it) {
      int c = tid + it * 256;
      int row = c >> 6, k4 = c & 63;
      float4 v = *reinterpret_cast<const float4*>(
          x + ((size_t)(b0 + row) * TT + t) * ID + k4 * 4);
      store4h(x_lds + row * LDX + k4 * 4, v.x, v.y, v.z, v.w);
    }
    __syncthreads();                                  // sync1: x_lds ready

    // ---- B: gate_x MFMA (independent of h -> before the poll) ----
    f32x4 gx = {0.f, 0.f, 0.f, 0.f};
    {
      const f16* pa = x_lds + (lane & 15) * LDX + (lane >> 4) * 8;
      const f16* pb = wx_lds + ((w >> 1) * 32 + (w & 1) * 16 + (lane & 15)) * LDX + (lane >> 4) * 8;
      #pragma unroll
      for (int ks = 0; ks < 8; ++ks) {
        f16x8 a = *reinterpret_cast<const f16x8*>(pa + ks * 32);
        f16x8 b = *reinterpret_cast<const f16x8*>(pb + ks * 32);
        gx = __builtin_amdgcn_mfma_f32_16x16x32_f16(a, b, gx, 0, 0, 0);
      }
    }

    // ---- C: wait for h_t (flag = count of published steps; h_0 via memset) ----
    if (t > 0) {
      if (w == 0) {
        int v;
        do { v = __hip_atomic_load(pollflag, __ATOMIC_RELAXED, __HIP_MEMORY_SCOPE_SYSTEM);
        } while (!__all(v >= t));
      }
      __syncthreads();                                // sync2: h_t visible
    }

    // ---- D: bypassing read of h_t -> h_lds ----
    {
      const u64* hsrc = (const u64*)(hbuf + (size_t)(t & 1) * (BB * HH) + (size_t)b0 * HH);
      #pragma unroll
      for (int it = 0; it < 16; ++it) {
        int idx = tid + it * 256;
        int row = idx >> 8, c4 = idx & 255;           // 256 u64 per row
        u64 v = __hip_atomic_load(hsrc + row * 256 + c4,
                                  __ATOMIC_RELAXED, __HIP_MEMORY_SCOPE_SYSTEM);
        *reinterpret_cast<u64*>(h_lds + row * LDH + c4 * 4) = v;
      }
    }
    __syncthreads();                                  // sync3: h_lds ready

    // ---- E: gate_h MFMA: wave w -> ntile=w&1, khalf=w>>1 ----
    f32x4 gh = {0.f, 0.f, 0.f, 0.f};
    {
      const f16* pa = h_lds + (lane & 15) * LDH + (lane >> 4) * 8 + (w >> 1) * 512;
      const f16* pb = wh_lds + ((w & 1) * 16 + (lane & 15)) * LDH + (lane >> 4) * 8 + (w >> 1) * 512;
      #pragma unroll
      for (int ks = 0; ks < 16; ++ks) {
        f16x8 a = *reinterpret_cast<const f16x8*>(pa + ks * 32);
        f16x8 b = *reinterpret_cast<const f16x8*>(pb + ks * 32);
        gh = __builtin_amdgcn_mfma_f32_16x16x32_f16(a, b, gh, 0, 0, 0);
      }
    }

    // ---- F: waves 2,3 export gh partial (khalf1) + gx (i_i) ----
    if (w >= 2) {
      float* dgh = xchg + (w & 1) * 272;              // 16*17
      float* dgx = xchg + (2 + (w & 1)) * 272;
      #pragma unroll
      for (int r = 0; r < 4; ++r) {
        dgh[(row4 + r) * 17 + col] = gh[r];
        dgx[(row4 + r) * 17 + col] = gx[r];
      }
    }
    __syncthreads();                                  // sync4: xchg ready

    // ---- G: pointwise GRU (waves 0,1), f32 masters; h' f16 -> hstage ----
    if (w < 2) {
      const float* sgh = xchg + w * 272;
      const float* sgx = xchg + (2 + w) * 272;
      const int c2 = (w & 1) * 16 + col;
      float hmv[4] = {hm0, hm1, hm2, hm3};
      float hn[4];
      #pragma unroll
      for (int r = 0; r < 4; ++r) {
        float ghf = gh[r] + sgh[(row4 + r) * 17 + col] + bh_r;
        float ir  = gx[r] + bxr_r;
        float ii  = sgx[(row4 + r) * 17 + col] + bxi_r;
        float rg  = 1.f / (1.f + __expf(-ir));
        float ig  = 1.f / (1.f + __expf(-ii));
        float z   = rg * ghf;
        z = fminf(fmaxf(z, -15.f), 15.f);
        float e   = __expf(-2.f * z);
        float ng  = (1.f - e) / (1.f + e);
        float h_  = ng + ig * (hmv[r] - ng);
        hn[r] = h_;
        hstage[(row4 + r) * LDS_HS + c2] = (f16)h_;
      }
      hm0 = hn[0]; hm1 = hn[1]; hm2 = hn[2]; hm3 = hn[3];
    }
    __syncthreads();                                  // sync5: hstage ready

    // ---- H: wave 0 publishes h' (row-major, bypassing) + flag ----
    if (w == 0) {
      u64* hd = (u64*)(hbuf + (size_t)((t + 1) & 1) * (BB * HH));
      #pragma unroll
      for (int u = 0; u < 2; ++u) {
        int idx = lane + u * 64;                      // 0..127
        int r = idx >> 3, q = idx & 7;                // 16 rows x 8 col-quads
        u64 v = *reinterpret_cast<const u64*>(hstage + r * LDS_HS + q * 4);
        __hip_atomic_store(hd + (size_t)(b0 + r) * 256 + (j0 >> 2) + q, v,
                           __ATOMIC_RELAXED, __HIP_MEMORY_SCOPE_SYSTEM);
      }
      asm volatile("s_waitcnt vmcnt(0)" ::: "memory"); // order data before flag
      __builtin_amdgcn_sched_barrier(0);
      if (lane == 0)
        __hip_atomic_store(myflag, t + 1, __ATOMIC_RELAXED, __HIP_MEMORY_SCOPE_SYSTEM);
    }
    // no trailing barrier: next step's sync1 isolates LDS reuse
  }

  // ---- export final h (f32 masters) for FC ----
  if (w < 2) {
    float hmv[4] = {hm0, hm1, hm2, hm3};
    #pragma unroll
    for (int r = 0; r < 4; ++r)
      hfin[(size_t)(b0 + row4 + r) * HH + jc] = hmv[r];
  }
}

// out[b][o] = sum_k hfin[b][k] * Wfc[o][k] + bfc[o];  128x256, K=1024.
__global__ __launch_bounds__(64) void fc_kernel(
    const float* __restrict__ hfin, const float* __restrict__ Wfc,
    const float* __restrict__ bfc, float* __restrict__ out)
{
  const int lane = threadIdx.x;
  const int mb = blockIdx.x >> 4, nb = blockIdx.x & 15;
  const int col = lane & 15, row4 = (lane >> 4) * 4;
  const float* pa = hfin + (size_t)(mb * 16 + (lane & 15)) * HH + (lane >> 4) * 8;
  const float* pb = Wfc  + (size_t)(nb * 16 + (lane & 15)) * HH + (lane >> 4) * 8;
  f32x4 acc = {0.f, 0.f, 0.f, 0.f};
  for (int kc = 0; kc < 32; ++kc) {
    f16x8 a, b;
    #pragma unroll
    for (int e = 0; e < 8; ++e) {
      a[e] = (f16)pa[kc * 32 + e];
      b[e] = (f16)pb[kc * 32 + e];
    }
    acc = __builtin_amdgcn_mfma_f32_16x16x32_f16(a, b, acc, 0, 0, 0);
  }
  float bias = bfc[nb * 16 + col];
  #pragma unroll
  for (int r = 0; r < 4; ++r)
    out[(size_t)(mb * 16 + row4 + r) * 256 + nb * 16 + col] = acc[r] + bias;
}

extern "C" void kernel_launch(void* const* d_in, const int* in_sizes, int n_in,
                              void* d_out, int out_size, void* d_ws, size_t ws_size,
                              hipStream_t stream) {
  const float* x   = (const float*)d_in[0];
  const float* Wx  = (const float*)d_in[1];
  const float* bx  = (const float*)d_in[2];
  const float* Wh  = (const float*)d_in[3];
  const float* bh  = (const float*)d_in[4];
  const float* Wfc = (const float*)d_in[5];
  const float* bfc = (const float*)d_in[6];
  float* out = (float*)d_out;

  char* ws = (char*)d_ws;
  f16*   hbuf  = (f16*)ws;                 // 2*128*1024*2  = 524288 B
  float* hfin  = (float*)(ws + 524288);    // 128*1024*4    = 524288 B
  int*   flags = (int*)(ws + 1048576);     // 8*32*16*4     = 16384 B

  hipMemsetAsync(hbuf, 0, 262144, stream); // h_0 = 0 (parity-0 buffer)
  hipMemsetAsync(flags, 0, 16384, stream); // flag 0 == "h_0 published"

  (void)hipFuncSetAttribute((const void*)rnn_core,
                            hipFuncAttributeMaxDynamicSharedMemorySize, LDS_SIZE);

  void* args[8];
  args[0] = (void*)&x;    args[1] = (void*)&Wx;   args[2] = (void*)&bx;
  args[3] = (void*)&Wh;   args[4] = (void*)&bh;   args[5] = (void*)&hbuf;
  args[6] = (void*)&hfin; args[7] = (void*)&flags;
  hipError_t err = hipLaunchCooperativeKernel((void*)rnn_core, dim3(256), dim3(256),
                                              args, LDS_SIZE, stream);
  if (err != hipSuccess) {
    rnn_core<<<dim3(256), dim3(256), LDS_SIZE, stream>>>(x, Wx, bx, Wh, bh, hbuf, hfin, flags);
  }

  fc_kernel<<<dim3(128), dim3(64), 0, stream>>>(hfin, Wfc, bfc, out);
}

// Round 4
// 4091.533 us; speedup vs baseline: 2.3227x; 1.5861x over previous
//
#include <hip/hip_runtime.h>
#include <hip/hip_fp16.h>

// IGIRNN persistent-scan kernel, round 4.
// Round-3 (aborted) used split inline-asm global loads: compiler vmcnt
// bookkeeping doesn't track asm loads -> register-copy/reuse hazard (rule
// #18 class). Round 4 keeps round-3's structure but uses ONLY round-2-proven
// primitives: relaxed SYSTEM-scope u64 atomic load/store (sc0 sc1 bypass,
// LLC-coherent). Round-2's serialization came from interleaving each load
// with a dependent ds_write (per-iter vmcnt drain); here all 32 loads issue
// back-to-back into registers (no intervening memory ops), so they pipeline,
// and MFMAs consume them with compiler-inserted progressive waits.
//
// Decomposition: 256 WGs x 256 thr (1/CU). 8 row-groups (16 batch rows) x
// 32 col-WGs (32 h cols). Wh/Wx slices persistent in LDS. Wave roles/step:
//  w0/w1: poll 16 flags each, 32 batched chunk loads, 16x2 MFMA (gate_h
//         K-half, both ntiles), exchange halves in LDS, pointwise, write hs.
//  w2:    publish own h_t chunk (2 u64 stores + vmcnt + flag), gx(t+1) g0.
//  w3:    gx(t+1) g1, prefetch x(t+2).
// 2 barriers/step. Chunks are 1KB in MFMA A-fragment order:
//   chunk[lane*16B] = h[b0+(lane&15)][j0c + (lane>>4)*8 .. +8].

#define BB 128
#define TT 1024
#define ID 256
#define HH 1024

using f16   = _Float16;
using f16x8 = __attribute__((ext_vector_type(8))) _Float16;
using f32x4 = __attribute__((ext_vector_type(4))) float;
typedef unsigned long long u64;

#define LDH 1032   // wh_lds row stride (f16): 2064B -> rotating banks
#define LDX 264    // wx_lds / x_lds row stride
#define HSW 40     // hstage row stride (f16, 80B; u64-aligned)

// LDS offsets (bytes)
#define OFF_WH   0                      // wh [32][LDH] f16      = 66048
#define OFF_WX   66048                  // wx [64][LDX] f16      = 33792
#define OFF_X    99840                  // x  [2][16][LDX] f16   = 16896
#define OFF_GX   116736                 // gx [2][4][272] f32    = 8704
#define OFF_GH   125440                 // gh [2][272] f32       = 2176
#define OFF_HS   127616                 // hs [2][16][HSW] f16   = 2560
#define LDS_SIZE 130176

__device__ __forceinline__ void store4h(f16* dst, float a, float b, float c, float d) {
  union { f16 h[4]; u64 u; } p;
  p.h[0] = (f16)a; p.h[1] = (f16)b; p.h[2] = (f16)c; p.h[3] = (f16)d;
  *reinterpret_cast<u64*>(dst) = p.u;
}

// one 16x16 gate_x tile, K=256
__device__ __forceinline__ f32x4 gx_tile(const f16* xb, const f16* wx, int gate, int nt, int lane) {
  f32x4 acc = {0.f, 0.f, 0.f, 0.f};
  const f16* pa = xb + (lane & 15) * LDX + (lane >> 4) * 8;
  const f16* pb = wx + (size_t)(gate * 32 + nt * 16 + (lane & 15)) * LDX + (lane >> 4) * 8;
  #pragma unroll
  for (int ks = 0; ks < 8; ++ks) {
    f16x8 a = *reinterpret_cast<const f16x8*>(pa + ks * 32);
    f16x8 b = *reinterpret_cast<const f16x8*>(pb + ks * 32);
    acc = __builtin_amdgcn_mfma_f32_16x16x32_f16(a, b, acc, 0, 0, 0);
  }
  return acc;
}

__device__ __forceinline__ void put_tile(float* dst, f32x4 v, int lane) {
  const int c = lane & 15, r4 = (lane >> 4) * 4;
  #pragma unroll
  for (int r = 0; r < 4; ++r) dst[(r4 + r) * 17 + c] = v[r];
}

__global__ __launch_bounds__(256, 1) void rnn_core(
    const float* __restrict__ x, const float* __restrict__ Wx, const float* __restrict__ bx,
    const float* __restrict__ Wh, const float* __restrict__ bh,
    f16* __restrict__ hbuf,      // [2][8 groups][32 writers][1KB chunk] = 512KB
    float* __restrict__ hfin,    // [128][1024] f32
    int* __restrict__ flags)     // [8*32] stamps, 64B-strided
{
  extern __shared__ char lds[];
  f16*   wh_lds = (f16*)(lds + OFF_WH);
  f16*   wx_lds = (f16*)(lds + OFF_WX);
  f16*   x_lds  = (f16*)(lds + OFF_X);    // [2][16][LDX]
  float* gxch   = (float*)(lds + OFF_GX); // [2][4][272]
  float* ghch   = (float*)(lds + OFF_GH); // [2][272]
  f16*   hs     = (f16*)(lds + OFF_HS);   // [2][16][HSW]

  const int tid  = threadIdx.x;
  const int lane = tid & 63;
  const int w    = tid >> 6;
  const int g    = blockIdx.x & 7;
  const int cw   = blockIdx.x >> 3;
  const int b0   = g * 16;
  const int j0   = cw * 32;
  const int col  = lane & 15;
  const int row4 = (lane >> 4) * 4;

  // ---- one-time weight staging ----
  for (int c = tid; c < 8192; c += 256) {
    int row = c >> 8, k4 = c & 255;
    float4 v = *reinterpret_cast<const float4*>(Wh + (size_t)(j0 + row) * HH + k4 * 4);
    store4h(wh_lds + row * LDH + k4 * 4, v.x, v.y, v.z, v.w);
  }
  for (int c = tid; c < 4096; c += 256) {
    int row = c >> 6, k4 = c & 63;
    int gr = (row < 32) ? (j0 + row) : (HH + j0 + row - 32);
    float4 v = *reinterpret_cast<const float4*>(Wx + (size_t)gr * ID + k4 * 4);
    store4h(wx_lds + row * LDX + k4 * 4, v.x, v.y, v.z, v.w);
  }
  // ---- prologue: x(0)->x_lds[0], x(1)->x_lds[1] ----
  for (int s = 0; s < 2; ++s)
    for (int c = tid; c < 1024; c += 256) {
      int row = c >> 6, k4 = c & 63;
      float4 v = *reinterpret_cast<const float4*>(
          x + ((size_t)(b0 + row) * TT + s) * ID + k4 * 4);
      store4h(x_lds + s * (16 * LDX) + row * LDX + k4 * 4, v.x, v.y, v.z, v.w);
    }
  __syncthreads();
  // gx(0): wave w -> tile w (gate w>>1, ntile w&1), parity 0
  put_tile(gxch + w * 272, gx_tile(x_lds, wx_lds, w >> 1, w & 1, lane), lane);

  const int jc = j0 + ((w & 1) << 4) + col;
  float bh_r = 0.f, bxr_r = 0.f, bxi_r = 0.f;
  if (w < 2) { bh_r = bh[jc]; bxr_r = bx[jc]; bxi_r = bx[HH + jc]; }
  float hm[4] = {0.f, 0.f, 0.f, 0.f};
  int* myflag = flags + (g * 32 + cw) * 16;

  for (int t = 0; t < TT; ++t) {
    __syncthreads();                                  // P1
    f32x4 acc0 = {0.f, 0.f, 0.f, 0.f}, acc1 = {0.f, 0.f, 0.f, 0.f};

    if (w == 2) {
      // ---- publish h_t chunk (fragment order) + flag; round-2-proven ----
      if (t > 0) {
        const u64* hsrc = (const u64*)(hs + (t & 1) * (16 * HSW));
        u64 v0 = hsrc[col * 10 + (lane >> 4) * 2];
        u64 v1 = hsrc[col * 10 + (lane >> 4) * 2 + 1];
        u64* hd = (u64*)((char*)hbuf +
                         (((size_t)(t & 1) * 256) + g * 32 + cw) * 1024) + lane * 2;
        __hip_atomic_store(hd,     v0, __ATOMIC_RELAXED, __HIP_MEMORY_SCOPE_SYSTEM);
        __hip_atomic_store(hd + 1, v1, __ATOMIC_RELAXED, __HIP_MEMORY_SCOPE_SYSTEM);
        asm volatile("s_waitcnt vmcnt(0)" ::: "memory");  // data before flag
        if (lane == 0)
          __hip_atomic_store(myflag, t, __ATOMIC_RELAXED, __HIP_MEMORY_SCOPE_SYSTEM);
      }
      // ---- gx(t+1), gate 0 tiles (off critical path) ----
      if (t + 1 < TT) {
        const f16* xb = x_lds + ((t + 1) & 1) * (16 * LDX);
        float* gdst = gxch + ((t + 1) & 1) * 1088;
        put_tile(gdst + 0 * 272, gx_tile(xb, wx_lds, 0, 0, lane), lane);
        put_tile(gdst + 1 * 272, gx_tile(xb, wx_lds, 0, 1, lane), lane);
      }
    } else if (w == 3) {
      // ---- gx(t+1), gate 1 tiles ----
      if (t + 1 < TT) {
        const f16* xb = x_lds + ((t + 1) & 1) * (16 * LDX);
        float* gdst = gxch + ((t + 1) & 1) * 1088;
        put_tile(gdst + 2 * 272, gx_tile(xb, wx_lds, 1, 0, lane), lane);
        put_tile(gdst + 3 * 272, gx_tile(xb, wx_lds, 1, 1, lane), lane);
      }
      // ---- prefetch x(t+2) -> x_lds[t&1] ----
      if (t + 2 < TT) {
        f16* xd = x_lds + (t & 1) * (16 * LDX);
        #pragma unroll
        for (int it = 0; it < 16; ++it) {
          int c = lane + it * 64;
          int row = c >> 6, k4 = c & 63;
          float4 v = *reinterpret_cast<const float4*>(
              x + ((size_t)(b0 + row) * TT + (t + 2)) * ID + k4 * 4);
          store4h(xd + row * LDX + k4 * 4, v.x, v.y, v.z, v.w);
        }
      }
    } else {
      // ---- consumers: wave w eats K-chunks [w*16, w*16+16) ----
      if (t > 0) {
        const int jm = (w << 4) | (lane & 15);
        const bool need = (lane < 16) && (jm != cw);
        const int* fp = flags + (g * 32 + jm) * 16;
        int v;
        do { v = need ? __hip_atomic_load(fp, __ATOMIC_RELAXED, __HIP_MEMORY_SCOPE_SYSTEM) : t;
        } while (!__all(v >= t));

        // 32 independent u64 bypass loads, back-to-back (no intervening
        // memory ops -> they pipeline; waits appear only before uses).
        const u64* cb = (const u64*)((const char*)hbuf +
            (((size_t)(t & 1) * 256) + g * 32 + (w << 4)) * 1024) + lane * 2;
        u64 rb[32];
        #pragma unroll
        for (int i = 0; i < 16; ++i) {
          rb[2 * i]     = __hip_atomic_load(cb + i * 128,
                              __ATOMIC_RELAXED, __HIP_MEMORY_SCOPE_SYSTEM);
          rb[2 * i + 1] = __hip_atomic_load(cb + i * 128 + 1,
                              __ATOMIC_RELAXED, __HIP_MEMORY_SCOPE_SYSTEM);
        }
        // own chunk: global copy races with own wave-2 store -> use LDS copy
        const int own = ((cw >> 4) == w) ? (cw & 15) : -1;
        u64 o0 = 0, o1 = 0;
        if (own >= 0) {
          const u64* hsrc = (const u64*)(hs + (t & 1) * (16 * HSW));
          o0 = hsrc[col * 10 + (lane >> 4) * 2];
          o1 = hsrc[col * 10 + (lane >> 4) * 2 + 1];
        }
        const f16* wb = wh_lds + col * LDH + (lane >> 4) * 8;
        #pragma unroll
        for (int i = 0; i < 16; ++i) {
          u64 lo = rb[2 * i], hi = rb[2 * i + 1];
          if (i == own) { lo = o0; hi = o1; }     // uniform select, no indexing
          union { u64 q[2]; f16x8 v8; } uu;
          uu.q[0] = lo; uu.q[1] = hi;
          const int j = (w << 4) + i;
          f16x8 bv0 = *reinterpret_cast<const f16x8*>(wb + j * 32);
          f16x8 bv1 = *reinterpret_cast<const f16x8*>(wb + 16 * LDH + j * 32);
          acc0 = __builtin_amdgcn_mfma_f32_16x16x32_f16(uu.v8, bv0, acc0, 0, 0, 0);
          acc1 = __builtin_amdgcn_mfma_f32_16x16x32_f16(uu.v8, bv1, acc1, 0, 0, 0);
        }
      }
      // export cross half: w0 gives ntile1 partial, w1 gives ntile0 partial
      put_tile(ghch + w * 272, (w == 0) ? acc1 : acc0, lane);
    }
    __syncthreads();                                  // P2

    if (w < 2) {
      const float* part = ghch + (1 - w) * 272;
      const float* gxr  = gxch + (t & 1) * 1088 + w * 272;        // i_r, ntile w
      const float* gxi  = gxch + (t & 1) * 1088 + (2 + w) * 272;  // i_i, ntile w
      f16* hd = hs + ((t + 1) & 1) * (16 * HSW);
      #pragma unroll
      for (int r = 0; r < 4; ++r) {
        float own_p = (w == 0) ? acc0[r] : acc1[r];
        float ghf = own_p + part[(row4 + r) * 17 + col] + bh_r;
        float ir  = gxr[(row4 + r) * 17 + col] + bxr_r;
        float ii  = gxi[(row4 + r) * 17 + col] + bxi_r;
        float rg  = 1.f / (1.f + __expf(-ir));
        float ig  = 1.f / (1.f + __expf(-ii));
        float z   = rg * ghf;
        z = fminf(fmaxf(z, -15.f), 15.f);
        float e   = __expf(-2.f * z);
        float ng  = (1.f - e) / (1.f + e);
        float h_  = ng + ig * (hm[r] - ng);
        hm[r] = h_;
        hd[(row4 + r) * HSW + ((w & 1) << 4) + col] = (f16)h_;
      }
    }
  }

  if (w < 2) {
    #pragma unroll
    for (int r = 0; r < 4; ++r)
      hfin[(size_t)(b0 + row4 + r) * HH + jc] = hm[r];
  }
}

// out[b][o] = hfin[b][:] . Wfc[o][:] + bfc[o];  128x256, K=1024.
__global__ __launch_bounds__(64) void fc_kernel(
    const float* __restrict__ hfin, const float* __restrict__ Wfc,
    const float* __restrict__ bfc, float* __restrict__ out)
{
  const int lane = threadIdx.x;
  const int mb = blockIdx.x >> 4, nb = blockIdx.x & 15;
  const int col = lane & 15, row4 = (lane >> 4) * 4;
  const float* pa = hfin + (size_t)(mb * 16 + (lane & 15)) * HH + (lane >> 4) * 8;
  const float* pb = Wfc  + (size_t)(nb * 16 + (lane & 15)) * HH + (lane >> 4) * 8;
  f32x4 acc = {0.f, 0.f, 0.f, 0.f};
  for (int kc = 0; kc < 32; ++kc) {
    f16x8 a, b;
    #pragma unroll
    for (int e = 0; e < 8; ++e) {
      a[e] = (f16)pa[kc * 32 + e];
      b[e] = (f16)pb[kc * 32 + e];
    }
    acc = __builtin_amdgcn_mfma_f32_16x16x32_f16(a, b, acc, 0, 0, 0);
  }
  float bias = bfc[nb * 16 + col];
  #pragma unroll
  for (int r = 0; r < 4; ++r)
    out[(size_t)(mb * 16 + row4 + r) * 256 + nb * 16 + col] = acc[r] + bias;
}

extern "C" void kernel_launch(void* const* d_in, const int* in_sizes, int n_in,
                              void* d_out, int out_size, void* d_ws, size_t ws_size,
                              hipStream_t stream) {
  const float* x   = (const float*)d_in[0];
  const float* Wx  = (const float*)d_in[1];
  const float* bx  = (const float*)d_in[2];
  const float* Wh  = (const float*)d_in[3];
  const float* bh  = (const float*)d_in[4];
  const float* Wfc = (const float*)d_in[5];
  const float* bfc = (const float*)d_in[6];
  float* out = (float*)d_out;

  char* ws = (char*)d_ws;
  f16*   hbuf  = (f16*)ws;                 // 512KB chunk exchange
  float* hfin  = (float*)(ws + 524288);    // 512KB
  int*   flags = (int*)(ws + 1048576);     // 16KB

  // flags must be zero at every launch (stamps monotone within one run)
  hipMemsetAsync(flags, 0, 16384, stream);

  (void)hipFuncSetAttribute((const void*)rnn_core,
                            hipFuncAttributeMaxDynamicSharedMemorySize, LDS_SIZE);

  void* args[8];
  args[0] = (void*)&x;    args[1] = (void*)&Wx;   args[2] = (void*)&bx;
  args[3] = (void*)&Wh;   args[4] = (void*)&bh;   args[5] = (void*)&hbuf;
  args[6] = (void*)&hfin; args[7] = (void*)&flags;
  hipError_t err = hipLaunchCooperativeKernel((void*)rnn_core, dim3(256), dim3(256),
                                              args, LDS_SIZE, stream);
  if (err != hipSuccess) {
    rnn_core<<<dim3(256), dim3(256), LDS_SIZE, stream>>>(x, Wx, bx, Wh, bh, hbuf, hfin, flags);
  }

  fc_kernel<<<dim3(128), dim3(64), 0, stream>>>(hfin, Wfc, bfc, out);
}

// Round 6
// 3999.564 us; speedup vs baseline: 2.3761x; 1.0230x over previous
//
#include <hip/hip_runtime.h>
#include <hip/hip_fp16.h>

// IGIRNN persistent-scan kernel, round 6 (= round-5 design, two fixes).
// Fix 1: gather asm uses 64-bit vaddr form (global_load_dwordx4 v, v[a:b],
//   off offset:N sc0 sc1) -- the saddr form failed: compiler couldn't prove
//   base uniform and put it in a VGPR pair (invalid operand).
// Fix 2: LDS padding (LDH=1042) broke b128/b64 alignment (odd rows 4B-
//   aligned); alignment forces stride%16B==0, which padding can't de-
//   conflict (rows 8 apart always alias). Use T2 XOR swizzle instead:
//   LDH=1024 exact, k_byte ^= (row&3)<<4. Mask bits 4-5 commute with the
//   (lane>>4)*16 quad offset -> hoists to one per-lane constant; <=2-way
//   conflicts (free, m136).
// Structure (round 5): TRANSPOSED tiles gate^T[j][batch] so pointwise
// thread owns 4 consecutive h-cols of one batch row -> publish is ONE
// contiguous 8B bypass store into fragment-order chunks; no LDS transpose,
// no publisher wave, ONE barrier/step. Monolithic-asm 16-deep gather with
// single vmcnt(0). Waves: w -> ntile=w>>1, K-half=w&1; after barrier even
// waves pointwise+publish+flag, odd waves gx(t+1)+x(t+2) prefetch.

#define BB 128
#define TT 1024
#define ID 256
#define HH 1024

using f16   = _Float16;
using f16x8 = __attribute__((ext_vector_type(8))) _Float16;
using f32x4 = __attribute__((ext_vector_type(4))) float;
typedef unsigned long long u64;

// LDS byte offsets (rows exact-power-of-2 strides + XOR swizzle)
#define OFF_WH   0        // wh [32][2048B]            = 65536
#define OFF_WX   65536    // wx [64][512B]             = 32768
#define OFF_X    98304    // x  [2][16][512B]          = 16384
#define OFF_GX   114688   // gx [2][4][272] f32        = 8704
#define OFF_GH   123392   // gh [2][2][272] f32        = 4352
#define LDS_SIZE 127744

#define SWZ(row, kbyte) ((kbyte) ^ (((row) & 3) << 4))

__device__ __forceinline__ void store4h(f16* dst, float a, float b, float c, float d) {
  union { f16 h[4]; u64 u; } p;
  p.h[0] = (f16)a; p.h[1] = (f16)b; p.h[2] = (f16)c; p.h[3] = (f16)d;
  *reinterpret_cast<u64*>(dst) = p.u;
}

// TRANSPOSED gate_x tile: D[j][batch] = Wx . x^T, K=256 (swizzled reads)
__device__ __forceinline__ f32x4 gx_tile(const char* xb, const char* wxb,
                                         int gate, int nt, int lane) {
  f32x4 acc = {0.f, 0.f, 0.f, 0.f};
  const int arow = gate * 32 + nt * 16 + (lane & 15);
  const int brow = lane & 15;
  const int kq   = (lane >> 4) * 16;
  const char* pa = wxb + arow * 512 + (kq ^ ((arow & 3) << 4));
  const char* pb = xb  + brow * 512 + (kq ^ ((brow & 3) << 4));
  #pragma unroll
  for (int ks = 0; ks < 8; ++ks) {
    f16x8 a = *reinterpret_cast<const f16x8*>(pa + ks * 64);
    f16x8 b = *reinterpret_cast<const f16x8*>(pb + ks * 64);
    acc = __builtin_amdgcn_mfma_f32_16x16x32_f16(a, b, acc, 0, 0, 0);
  }
  return acc;
}

__device__ __forceinline__ void put_tile(float* dst, f32x4 v, int lane) {
  const int c = lane & 15, r4 = (lane >> 4) * 4;
  #pragma unroll
  for (int r = 0; r < 4; ++r) dst[(r4 + r) * 17 + c] = v[r];
}

__global__ __launch_bounds__(256, 1) void rnn_core(
    const float* __restrict__ x, const float* __restrict__ Wx, const float* __restrict__ bx,
    const float* __restrict__ Wh, const float* __restrict__ bh,
    f16* __restrict__ hbuf,      // [2 parity][8 grp][32 wg][1KB chunk] = 512KB
    float* __restrict__ hfin,    // [128][1024] f32
    int* __restrict__ flags)     // [8][32][2] stamps, 64B-strided
{
  extern __shared__ char lds[];
  char*  whb  = lds + OFF_WH;
  char*  wxb  = lds + OFF_WX;
  char*  xbuf = lds + OFF_X;              // [2][16][512B]
  float* gxch = (float*)(lds + OFF_GX);   // [2][4][272]  q = gate*2+nt
  float* ghch = (float*)(lds + OFF_GH);   // [2][2][272]  per ntile

  const int tid  = threadIdx.x;
  const int lane = tid & 63;
  const int w    = tid >> 6;
  const int g    = blockIdx.x & 7;
  const int cw   = blockIdx.x >> 3;
  const int b0   = g * 16;
  const int j0   = cw * 32;
  const int col  = lane & 15;            // batch row (transposed world)
  const int row4 = (lane >> 4) * 4;      // local j base
  const int nt   = w >> 1;               // wave's ntile
  const int c0   = (w & 1) * 16;         // wave's first K-chunk

  // ---- one-time weight staging (swizzled LDS writes) ----
  for (int c = tid; c < 8192; c += 256) {            // Wh rows j0..j0+31
    int row = c >> 8, k4 = c & 255;
    float4 v = *reinterpret_cast<const float4*>(Wh + (size_t)(j0 + row) * HH + k4 * 4);
    store4h((f16*)(whb + row * 2048 + SWZ(row, k4 * 8)), v.x, v.y, v.z, v.w);
  }
  for (int c = tid; c < 4096; c += 256) {            // Wx: i_r j0..+31, i_i 1024+j0..+31
    int row = c >> 6, k4 = c & 63;
    int gr = (row < 32) ? (j0 + row) : (HH + j0 + row - 32);
    float4 v = *reinterpret_cast<const float4*>(Wx + (size_t)gr * ID + k4 * 4);
    store4h((f16*)(wxb + row * 512 + SWZ(row, k4 * 8)), v.x, v.y, v.z, v.w);
  }
  // ---- prologue: x(0)->slot0, x(1)->slot1 ----
  for (int s = 0; s < 2; ++s)
    for (int c = tid; c < 1024; c += 256) {
      int row = c >> 6, k4 = c & 63;
      float4 v = *reinterpret_cast<const float4*>(
          x + ((size_t)(b0 + row) * TT + s) * ID + k4 * 4);
      store4h((f16*)(xbuf + s * 8192 + row * 512 + SWZ(row, k4 * 8)), v.x, v.y, v.z, v.w);
    }
  __syncthreads();
  // gx(0): wave w -> q=w (gate=w>>1, nt=w&1), parity 0
  put_tile(gxch + w * 272, gx_tile(xbuf, wxb, w >> 1, w & 1, lane), lane);

  // per-thread j-range (even waves): j = j0 + nt*16 + row4 + r
  float4 bh4 = {0,0,0,0}, bxr4 = {0,0,0,0}, bxi4 = {0,0,0,0};
  if (!(w & 1)) {
    bh4  = *reinterpret_cast<const float4*>(bh + j0 + nt * 16 + row4);
    bxr4 = *reinterpret_cast<const float4*>(bx + j0 + nt * 16 + row4);
    bxi4 = *reinterpret_cast<const float4*>(bx + HH + j0 + nt * 16 + row4);
  }
  float hm[4] = {0.f, 0.f, 0.f, 0.f};     // h[b0+col][j0+nt*16+row4+r]
  int* myflag = flags + ((g * 32 + cw) * 2 + nt) * 16;

  // hoisted per-lane constants for the wh fragment reads (swizzle commutes)
  const char* wbbase = whb + (size_t)(nt * 16 + (lane & 15)) * 2048 + c0 * 64
                       + (((lane >> 4) * 16) ^ ((col & 3) << 4));
  const unsigned gvo = (unsigned)(col * 64 + (lane >> 4) * 16);

  for (int t = 0; t < TT; ++t) {
    // ======== region A: consume h(t), MFMA gate_h^T ========
    f32x4 acc = {0.f, 0.f, 0.f, 0.f};
    if (t > 0) {
      // poll this wave's 16 source chunks, both nt flags (lanes 0..31)
      const int* fp = flags + ((g * 32 + c0 + (lane & 15)) * 2 + ((lane >> 4) & 1)) * 16;
      int v;
      do { v = (lane < 32) ? __hip_atomic_load(fp, __ATOMIC_RELAXED, __HIP_MEMORY_SCOPE_SYSTEM) : t;
      } while (!__all(v >= t));

      // monolithic 16-deep gather, 64-bit vaddr form, one vmcnt(0)
      u64 ad0 = (u64)((const char*)hbuf +
          (((size_t)(t & 1) * 256 + g * 32 + c0) << 10)) + gvo;
      u64 ad1 = ad0 + 4096, ad2 = ad0 + 8192, ad3 = ad0 + 12288;
      f32x4 f0, f1, f2, f3, f4, f5, f6, f7, f8, f9, f10, f11, f12, f13, f14, f15;
      asm volatile(
        "global_load_dwordx4 %0, %16, off sc0 sc1\n\t"
        "global_load_dwordx4 %1, %16, off offset:1024 sc0 sc1\n\t"
        "global_load_dwordx4 %2, %16, off offset:2048 sc0 sc1\n\t"
        "global_load_dwordx4 %3, %16, off offset:3072 sc0 sc1\n\t"
        "global_load_dwordx4 %4, %17, off sc0 sc1\n\t"
        "global_load_dwordx4 %5, %17, off offset:1024 sc0 sc1\n\t"
        "global_load_dwordx4 %6, %17, off offset:2048 sc0 sc1\n\t"
        "global_load_dwordx4 %7, %17, off offset:3072 sc0 sc1\n\t"
        "global_load_dwordx4 %8, %18, off sc0 sc1\n\t"
        "global_load_dwordx4 %9, %18, off offset:1024 sc0 sc1\n\t"
        "global_load_dwordx4 %10, %18, off offset:2048 sc0 sc1\n\t"
        "global_load_dwordx4 %11, %18, off offset:3072 sc0 sc1\n\t"
        "global_load_dwordx4 %12, %19, off sc0 sc1\n\t"
        "global_load_dwordx4 %13, %19, off offset:1024 sc0 sc1\n\t"
        "global_load_dwordx4 %14, %19, off offset:2048 sc0 sc1\n\t"
        "global_load_dwordx4 %15, %19, off offset:3072 sc0 sc1\n\t"
        "s_waitcnt vmcnt(0)"
        : "=&v"(f0), "=&v"(f1), "=&v"(f2), "=&v"(f3),
          "=&v"(f4), "=&v"(f5), "=&v"(f6), "=&v"(f7),
          "=&v"(f8), "=&v"(f9), "=&v"(f10), "=&v"(f11),
          "=&v"(f12), "=&v"(f13), "=&v"(f14), "=&v"(f15)
        : "v"(ad0), "v"(ad1), "v"(ad2), "v"(ad3)
        : "memory");

      // A = Wh fragment (lane&15 = j-local), B = h fragment (lane&15 = batch)
      #define MF(i, F) { f16x8 a_ = *reinterpret_cast<const f16x8*>(wbbase + (i) * 64); \
        acc = __builtin_amdgcn_mfma_f32_16x16x32_f16(a_, *reinterpret_cast<f16x8*>(&F), acc, 0, 0, 0); }
      MF(0, f0)  MF(1, f1)  MF(2, f2)  MF(3, f3)
      MF(4, f4)  MF(5, f5)  MF(6, f6)  MF(7, f7)
      MF(8, f8)  MF(9, f9)  MF(10, f10) MF(11, f11)
      MF(12, f12) MF(13, f13) MF(14, f14) MF(15, f15)
      #undef MF
    }
    if (w & 1) put_tile(ghch + (t & 1) * 544 + nt * 272, acc, lane);

    __syncthreads();   // the ONE barrier per step

    // ======== region B ========
    if (!(w & 1)) {
      // pointwise: thread owns batch=col, j=j0+nt*16+row4+r
      const float* part = ghch + (t & 1) * 544 + nt * 272;
      const float* gxr  = gxch + (t & 1) * 1088 + nt * 272;        // i_r
      const float* gxi  = gxch + (t & 1) * 1088 + (2 + nt) * 272;  // i_i
      float hn[4];
      #pragma unroll
      for (int r = 0; r < 4; ++r) {
        float ghf = acc[r] + part[(row4 + r) * 17 + col] + ((const float*)&bh4)[r];
        float ir  = gxr[(row4 + r) * 17 + col] + ((const float*)&bxr4)[r];
        float ii  = gxi[(row4 + r) * 17 + col] + ((const float*)&bxi4)[r];
        float rg  = 1.f / (1.f + __expf(-ir));
        float ig  = 1.f / (1.f + __expf(-ii));
        float z   = rg * ghf;
        z = fminf(fmaxf(z, -15.f), 15.f);
        float e   = __expf(-2.f * z);
        float ng  = (1.f - e) / (1.f + e);
        float h_  = ng + ig * (hm[r] - ng);
        hm[r] = h_;
        hn[r] = h_;
      }
      // publish: ONE contiguous 8B bypass store (4 consecutive j, one row)
      union { f16 h[4]; u64 u; } p;
      p.h[0] = (f16)hn[0]; p.h[1] = (f16)hn[1]; p.h[2] = (f16)hn[2]; p.h[3] = (f16)hn[3];
      u64* hd = (u64*)((char*)hbuf +
          (((size_t)((t + 1) & 1) * 256 + g * 32 + cw) << 10)
          + col * 64 + nt * 32 + (lane >> 4) * 8);
      __hip_atomic_store(hd, p.u, __ATOMIC_RELAXED, __HIP_MEMORY_SCOPE_SYSTEM);
      asm volatile("s_waitcnt vmcnt(0)" ::: "memory");   // data before flag
      if (lane == 0)
        __hip_atomic_store(myflag, t + 1, __ATOMIC_RELAXED, __HIP_MEMORY_SCOPE_SYSTEM);
    } else {
      // gx(t+1) into parity (t+1): this wave's ntile, both gates
      if (t + 1 < TT) {
        const char* xb = xbuf + ((t + 1) & 1) * 8192;
        float* gdst = gxch + ((t + 1) & 1) * 1088;
        put_tile(gdst + nt * 272,       gx_tile(xb, wxb, 0, nt, lane), lane);
        put_tile(gdst + (2 + nt) * 272, gx_tile(xb, wxb, 1, nt, lane), lane);
      }
      // x(t+2) prefetch -> slot t&1 (w1 rows 0-7, w3 rows 8-15)
      if (t + 2 < TT) {
        char* xd = xbuf + (t & 1) * 8192;
        #pragma unroll
        for (int it = 0; it < 8; ++it) {
          int row = nt * 8 + it;
          float4 v = *reinterpret_cast<const float4*>(
              x + ((size_t)(b0 + row) * TT + (t + 2)) * ID + lane * 4);
          store4h((f16*)(xd + row * 512 + SWZ(row, lane * 8)), v.x, v.y, v.z, v.w);
        }
      }
    }
  }

  // ---- final h export: 4 consecutive j -> one float4 ----
  if (!(w & 1)) {
    float4 o; o.x = hm[0]; o.y = hm[1]; o.z = hm[2]; o.w = hm[3];
    *reinterpret_cast<float4*>(
        hfin + (size_t)(b0 + col) * HH + j0 + nt * 16 + row4) = o;
  }
}

// out[b][o] = hfin[b][:] . Wfc[o][:] + bfc[o];  128x256, K=1024.
__global__ __launch_bounds__(64) void fc_kernel(
    const float* __restrict__ hfin, const float* __restrict__ Wfc,
    const float* __restrict__ bfc, float* __restrict__ out)
{
  const int lane = threadIdx.x;
  const int mb = blockIdx.x >> 4, nb = blockIdx.x & 15;
  const int col = lane & 15, row4 = (lane >> 4) * 4;
  const float* pa = hfin + (size_t)(mb * 16 + (lane & 15)) * HH + (lane >> 4) * 8;
  const float* pb = Wfc  + (size_t)(nb * 16 + (lane & 15)) * HH + (lane >> 4) * 8;
  f32x4 acc = {0.f, 0.f, 0.f, 0.f};
  for (int kc = 0; kc < 32; ++kc) {
    f16x8 a, b;
    #pragma unroll
    for (int e = 0; e < 8; ++e) {
      a[e] = (f16)pa[kc * 32 + e];
      b[e] = (f16)pb[kc * 32 + e];
    }
    acc = __builtin_amdgcn_mfma_f32_16x16x32_f16(a, b, acc, 0, 0, 0);
  }
  float bias = bfc[nb * 16 + col];
  #pragma unroll
  for (int r = 0; r < 4; ++r)
    out[(size_t)(mb * 16 + row4 + r) * 256 + nb * 16 + col] = acc[r] + bias;
}

extern "C" void kernel_launch(void* const* d_in, const int* in_sizes, int n_in,
                              void* d_out, int out_size, void* d_ws, size_t ws_size,
                              hipStream_t stream) {
  const float* x   = (const float*)d_in[0];
  const float* Wx  = (const float*)d_in[1];
  const float* bx  = (const float*)d_in[2];
  const float* Wh  = (const float*)d_in[3];
  const float* bh  = (const float*)d_in[4];
  const float* Wfc = (const float*)d_in[5];
  const float* bfc = (const float*)d_in[6];
  float* out = (float*)d_out;

  char* ws = (char*)d_ws;
  f16*   hbuf  = (f16*)ws;                 // 512KB chunk exchange
  float* hfin  = (float*)(ws + 524288);    // 512KB
  int*   flags = (int*)(ws + 1048576);     // 32KB ([8][32][2] x 64B)

  hipMemsetAsync(flags, 0, 32768, stream); // stamps monotone within one run

  (void)hipFuncSetAttribute((const void*)rnn_core,
                            hipFuncAttributeMaxDynamicSharedMemorySize, LDS_SIZE);

  void* args[8];
  args[0] = (void*)&x;    args[1] = (void*)&Wx;   args[2] = (void*)&bx;
  args[3] = (void*)&Wh;   args[4] = (void*)&bh;   args[5] = (void*)&hbuf;
  args[6] = (void*)&hfin; args[7] = (void*)&flags;
  hipError_t err = hipLaunchCooperativeKernel((void*)rnn_core, dim3(256), dim3(256),
                                              args, LDS_SIZE, stream);
  if (err != hipSuccess) {
    rnn_core<<<dim3(256), dim3(256), LDS_SIZE, stream>>>(x, Wx, bx, Wh, bh, hbuf, hfin, flags);
  }

  fc_kernel<<<dim3(128), dim3(64), 0, stream>>>(hfin, Wfc, bfc, out);
}

// Round 8
// 3083.089 us; speedup vs baseline: 3.0824x; 1.2973x over previous
//
#include <hip/hip_runtime.h>
#include <hip/hip_fp16.h>

// IGIRNN persistent-scan kernel, round 8.
// Round-7 hang: FAST path used plain stores / sc0-only loads for cross-WG
// exchange -- below the device-scope memory model (G16: L1 can serve stale
// data even intra-XCD); consumer poll can spin forever. XCD-local coherence
// gamble DELETED. Round 8 = round-6-proven protocol (system-scope sc0 sc1
// intrinsics for poll/publish/flag; monolithic asm gather w/ internal
// vmcnt(0)) + two compile-proven round-7 wins:
//  (1) Wh/Wx A-fragments preloaded to REGISTERS (one-time): kills all weight
//      LDS reads = the 3.77e8 bank-conflict cycles of round 6.
//  (2) 4-way K-split dedup: each wave gathers 8 DISTINCT chunks (union of 4
//      waves = all 32 -> barrier preserves round-6 overwrite-safety proof),
//      computes BOTH ntiles, partials reduced via LDS 17-stride tiles.
//      Exchange volume halves: 64 -> 32 KB/WG/step (the per-WG floor).
// Roles/step: all waves poll+gather+MFMA (region A) -> barrier -> even waves
// reduce+pointwise+publish+flag, odd waves gx(t+1)+x(t+2) prefetch (region B).

#define BB 128
#define TT 1024
#define ID 256
#define HH 1024

using f16   = _Float16;
using f16x8 = __attribute__((ext_vector_type(8))) _Float16;
using f32x4 = __attribute__((ext_vector_type(4))) float;
typedef unsigned long long u64;

// LDS (bytes)
#define OFF_X    0        // x   [2][16][512B] f16, SWZ     = 16384
#define OFF_GX   16384    // gx  [2][4][272] f32            = 8704
#define OFF_GH   25088    // ghT [2][2][4][272] f32         = 17408
#define LDS_SIZE 42496

#define SWZ(row, kbyte) ((kbyte) ^ (((row) & 3) << 4))
#define MFMA16(a, b, c) __builtin_amdgcn_mfma_f32_16x16x32_f16(a, b, c, 0, 0, 0)

static __device__ __forceinline__ void store4h(f16* dst, float a, float b, float c, float d) {
  union { f16 h[4]; u64 u; } p;
  p.h[0] = (f16)a; p.h[1] = (f16)b; p.h[2] = (f16)c; p.h[3] = (f16)d;
  *reinterpret_cast<u64*>(dst) = p.u;
}

static __device__ __forceinline__ f16x8 cvt8(float4 a, float4 b) {
  f16x8 r;
  r[0] = (f16)a.x; r[1] = (f16)a.y; r[2] = (f16)a.z; r[3] = (f16)a.w;
  r[4] = (f16)b.x; r[5] = (f16)b.y; r[6] = (f16)b.z; r[7] = (f16)b.w;
  return r;
}

static __device__ __forceinline__ void put_tile(float* dst, f32x4 v, int lane) {
  const int c = lane & 15, r4 = (lane >> 4) * 4;
  #pragma unroll
  for (int r = 0; r < 4; ++r) dst[(r4 + r) * 17 + c] = v[r];
}

__global__ __launch_bounds__(256, 1) void rnn_core(
    const float* __restrict__ x, const float* __restrict__ Wx, const float* __restrict__ bx,
    const float* __restrict__ Wh, const float* __restrict__ bh,
    f16* __restrict__ hbuf,      // [2 parity][8 grp][32 wg][1KB chunk] = 512KB
    float* __restrict__ hfin,    // [128][1024] f32
    int* __restrict__ flags)     // [8][32][2] stamps, 64B-strided
{
  extern __shared__ char lds[];
  char*  xbuf = lds + OFF_X;
  float* gxch = (float*)(lds + OFF_GX);   // [2][4][272], q = gate*2 + nt
  float* ghT  = (float*)(lds + OFF_GH);   // [2][2][4][272]: [parity][nt][src]

  const int tid  = threadIdx.x;
  const int lane = tid & 63;
  const int w    = tid >> 6;
  const int g    = blockIdx.x & 7;
  const int cw   = blockIdx.x >> 3;
  const int b0   = g * 16;
  const int j0   = cw * 32;
  const int col  = lane & 15;
  const int quad = lane >> 4;
  const int row4 = quad * 4;
  const int nt   = w >> 1;               // even waves: output ntile; odd: gx ntile

  // ---- Wh A-fragments -> registers (ALL waves; K-chunks w*8..w*8+7) ----
  // whf[n*8+i][e] = Wh[j0+n*16+col][(w*8+i)*32 + quad*8 + e]
  f16x8 whf[16];
  #pragma unroll
  for (int n = 0; n < 2; ++n)
    #pragma unroll
    for (int i = 0; i < 8; ++i) {
      const float* p = Wh + (size_t)(j0 + n * 16 + col) * HH + ((w << 3) + i) * 32 + quad * 8;
      whf[n * 8 + i] = cvt8(*reinterpret_cast<const float4*>(p),
                            *reinterpret_cast<const float4*>(p + 4));
    }
  // ---- Wx A-fragments (odd waves; [gate][ks]) ----
  f16x8 wxf[16];
  if (w & 1) {
    #pragma unroll
    for (int g2 = 0; g2 < 2; ++g2)
      #pragma unroll
      for (int ks = 0; ks < 8; ++ks) {
        const float* p = Wx + (size_t)(g2 * HH + j0 + nt * 16 + col) * ID + ks * 32 + quad * 8;
        wxf[g2 * 8 + ks] = cvt8(*reinterpret_cast<const float4*>(p),
                                *reinterpret_cast<const float4*>(p + 4));
      }
  }

  // ---- prologue: stage x(0)->slot0, x(1)->slot1 ----
  for (int s = 0; s < 2; ++s)
    for (int c = tid; c < 1024; c += 256) {
      int row = c >> 6, k4 = c & 63;
      float4 v = *reinterpret_cast<const float4*>(
          x + ((size_t)(b0 + row) * TT + s) * ID + k4 * 4);
      store4h((f16*)(xbuf + s * 8192 + row * 512 + SWZ(row, k4 * 8)), v.x, v.y, v.z, v.w);
    }
  __syncthreads();

  // ---- prologue gx(0) (odd waves), parity 0 ----
  if (w & 1) {
    const char* pxb = xbuf + col * 512 + ((quad * 16) ^ ((col & 3) << 4));
    f32x4 a0 = {0,0,0,0}, a1 = {0,0,0,0};
    #pragma unroll
    for (int ks = 0; ks < 8; ++ks) {
      f16x8 bfr = *reinterpret_cast<const f16x8*>(pxb + ks * 64);
      a0 = MFMA16(wxf[ks], bfr, a0);
      a1 = MFMA16(wxf[8 + ks], bfr, a1);
    }
    put_tile(gxch + nt * 272, a0, lane);
    put_tile(gxch + (2 + nt) * 272, a1, lane);
  }

  // even-wave pointwise constants (j = j0 + nt*16 + row4 + r)
  float4 bh4 = {0,0,0,0}, bxr4 = {0,0,0,0}, bxi4 = {0,0,0,0};
  if (!(w & 1)) {
    bh4  = *reinterpret_cast<const float4*>(bh + j0 + nt * 16 + row4);
    bxr4 = *reinterpret_cast<const float4*>(bx + j0 + nt * 16 + row4);
    bxi4 = *reinterpret_cast<const float4*>(bx + HH + j0 + nt * 16 + row4);
  }
  float hm[4] = {0.f, 0.f, 0.f, 0.f};     // h[b0+col][j0+nt*16+row4+r]

  // invariant addresses
  const unsigned gvo = (unsigned)(col * 64 + quad * 16);
  const u64 hb0 = (u64)((const char*)hbuf + (((size_t)g * 32 + (w << 3)) << 10)) + gvo;
  const u64 hb1 = hb0 + (256ull << 10);
  const u64 pb0 = (u64)((char*)hbuf + (((size_t)g * 32 + cw) << 10))
                  + (unsigned)(col * 64 + nt * 32 + quad * 8);
  const u64 pb1 = pb0 + (256ull << 10);
  int* myflag = flags + ((g * 32 + cw) * 2 + nt) * 16;
  const int* pollp = flags + ((g * 32 + (w << 3) + (lane & 7)) * 2 + ((lane >> 3) & 1)) * 16;

  for (int t = 0; t < TT; ++t) {
    const int p = t & 1;
    // ======== region A: poll 16 flags -> gather 8 chunks -> 16 MFMAs ========
    f32x4 acc0 = {0,0,0,0}, acc1 = {0,0,0,0};
    if (t > 0) {
      int v;
      do { v = (lane < 16)
               ? __hip_atomic_load(pollp, __ATOMIC_RELAXED, __HIP_MEMORY_SCOPE_SYSTEM) : t;
      } while (!__all(v >= t));

      u64 ad0 = p ? hb1 : hb0;
      u64 ad1 = ad0 + 4096;
      f32x4 f0, f1, f2, f3, f4, f5, f6, f7;
      asm volatile(
        "global_load_dwordx4 %0, %8, off sc0 sc1\n\t"
        "global_load_dwordx4 %1, %8, off offset:1024 sc0 sc1\n\t"
        "global_load_dwordx4 %2, %8, off offset:2048 sc0 sc1\n\t"
        "global_load_dwordx4 %3, %8, off offset:3072 sc0 sc1\n\t"
        "global_load_dwordx4 %4, %9, off sc0 sc1\n\t"
        "global_load_dwordx4 %5, %9, off offset:1024 sc0 sc1\n\t"
        "global_load_dwordx4 %6, %9, off offset:2048 sc0 sc1\n\t"
        "global_load_dwordx4 %7, %9, off offset:3072 sc0 sc1\n\t"
        "s_waitcnt vmcnt(0)"
        : "=&v"(f0), "=&v"(f1), "=&v"(f2), "=&v"(f3),
          "=&v"(f4), "=&v"(f5), "=&v"(f6), "=&v"(f7)
        : "v"(ad0), "v"(ad1) : "memory");

      #define STEPM(i, F) { f16x8 bf_ = *reinterpret_cast<f16x8*>(&F); \
        acc0 = MFMA16(whf[i], bf_, acc0); acc1 = MFMA16(whf[8 + (i)], bf_, acc1); }
      STEPM(0, f0) STEPM(1, f1) STEPM(2, f2) STEPM(3, f3)
      STEPM(4, f4) STEPM(5, f5) STEPM(6, f6) STEPM(7, f7)
      #undef STEPM
    }
    // export partials (slot = src wave); even waves keep own-nt in register
    float* ghp = ghT + p * 2176;
    if (w == 0)      { put_tile(ghp + (4 + 0) * 272, acc1, lane); }
    else if (w == 1) { put_tile(ghp + 1 * 272, acc0, lane);
                       put_tile(ghp + (4 + 1) * 272, acc1, lane); }
    else if (w == 2) { put_tile(ghp + 2 * 272, acc0, lane); }
    else             { put_tile(ghp + 3 * 272, acc0, lane);
                       put_tile(ghp + (4 + 3) * 272, acc1, lane); }

    __syncthreads();                                  // the ONE barrier/step

    // ======== region B ========
    if (!(w & 1)) {
      // reduce 3 partials + own, pointwise, publish, flag
      const float* basep = ghp + nt * 4 * 272;
      const float* s0 = basep + ((w == 0) ? 1 : 0) * 272;
      const float* s1 = basep + ((w == 0) ? 2 : 1) * 272;
      const float* s2 = basep + 3 * 272;
      const float* gxr = gxch + p * 1088 + nt * 272;
      const float* gxi = gxch + p * 1088 + (2 + nt) * 272;
      f32x4 own = (w == 0) ? acc0 : acc1;
      float hn[4];
      #pragma unroll
      for (int r = 0; r < 4; ++r) {
        int idx = (row4 + r) * 17 + col;
        float ghf = own[r] + s0[idx] + s1[idx] + s2[idx] + ((const float*)&bh4)[r];
        float ir  = gxr[idx] + ((const float*)&bxr4)[r];
        float ii  = gxi[idx] + ((const float*)&bxi4)[r];
        float rg  = 1.f / (1.f + __expf(-ir));
        float ig  = 1.f / (1.f + __expf(-ii));
        float z   = rg * ghf;
        z = fminf(fmaxf(z, -15.f), 15.f);
        float e   = __expf(-2.f * z);
        float ng  = (1.f - e) / (1.f + e);
        float h_  = ng + ig * (hm[r] - ng);
        hm[r] = h_; hn[r] = h_;
      }
      union { f16 h[4]; u64 uu; } pk;
      pk.h[0] = (f16)hn[0]; pk.h[1] = (f16)hn[1]; pk.h[2] = (f16)hn[2]; pk.h[3] = (f16)hn[3];
      u64* adp = (u64*)(p ? pb0 : pb1);               // h(t+1) -> parity (t+1)&1
      __hip_atomic_store(adp, pk.uu, __ATOMIC_RELAXED, __HIP_MEMORY_SCOPE_SYSTEM);
      asm volatile("s_waitcnt vmcnt(0)" ::: "memory"); // data before flag
      if (lane == 0)
        __hip_atomic_store(myflag, t + 1, __ATOMIC_RELAXED, __HIP_MEMORY_SCOPE_SYSTEM);
    } else {
      // gx(t+1) -> gxch parity (t+1)&1
      if (t + 1 < TT) {
        const char* pxb = xbuf + ((t + 1) & 1) * 8192 + col * 512
                          + ((quad * 16) ^ ((col & 3) << 4));
        f32x4 a0 = {0,0,0,0}, a1 = {0,0,0,0};
        #pragma unroll
        for (int ks = 0; ks < 8; ++ks) {
          f16x8 bfr = *reinterpret_cast<const f16x8*>(pxb + ks * 64);
          a0 = MFMA16(wxf[ks], bfr, a0);
          a1 = MFMA16(wxf[8 + ks], bfr, a1);
        }
        float* gdst = gxch + ((t + 1) & 1) * 1088;
        put_tile(gdst + nt * 272, a0, lane);
        put_tile(gdst + (2 + nt) * 272, a1, lane);
      }
      // x(t+2) prefetch -> slot t&1 (w1 rows 0-7, w3 rows 8-15)
      if (t + 2 < TT) {
        char* xd = xbuf + p * 8192;
        #pragma unroll
        for (int it = 0; it < 8; ++it) {
          int row = nt * 8 + it;
          float4 v = *reinterpret_cast<const float4*>(
              x + ((size_t)(b0 + row) * TT + (t + 2)) * ID + lane * 4);
          store4h((f16*)(xd + row * 512 + SWZ(row, lane * 8)), v.x, v.y, v.z, v.w);
        }
      }
    }
  }

  // ---- final h export ----
  if (!(w & 1)) {
    float4 o; o.x = hm[0]; o.y = hm[1]; o.z = hm[2]; o.w = hm[3];
    *reinterpret_cast<float4*>(hfin + (size_t)(b0 + col) * HH + j0 + nt * 16 + row4) = o;
  }
}

// out[b][o] = hfin[b][:] . Wfc[o][:] + bfc[o];  128x256, K=1024.
__global__ __launch_bounds__(64) void fc_kernel(
    const float* __restrict__ hfin, const float* __restrict__ Wfc,
    const float* __restrict__ bfc, float* __restrict__ out)
{
  const int lane = threadIdx.x;
  const int mb = blockIdx.x >> 4, nb = blockIdx.x & 15;
  const int col = lane & 15, row4 = (lane >> 4) * 4;
  const float* pa = hfin + (size_t)(mb * 16 + (lane & 15)) * HH + (lane >> 4) * 8;
  const float* pb = Wfc  + (size_t)(nb * 16 + (lane & 15)) * HH + (lane >> 4) * 8;
  f32x4 acc = {0.f, 0.f, 0.f, 0.f};
  for (int kc = 0; kc < 32; ++kc) {
    f16x8 a, b;
    #pragma unroll
    for (int e = 0; e < 8; ++e) {
      a[e] = (f16)pa[kc * 32 + e];
      b[e] = (f16)pb[kc * 32 + e];
    }
    acc = __builtin_amdgcn_mfma_f32_16x16x32_f16(a, b, acc, 0, 0, 0);
  }
  float bias = bfc[nb * 16 + col];
  #pragma unroll
  for (int r = 0; r < 4; ++r)
    out[(size_t)(mb * 16 + row4 + r) * 256 + nb * 16 + col] = acc[r] + bias;
}

extern "C" void kernel_launch(void* const* d_in, const int* in_sizes, int n_in,
                              void* d_out, int out_size, void* d_ws, size_t ws_size,
                              hipStream_t stream) {
  const float* x   = (const float*)d_in[0];
  const float* Wx  = (const float*)d_in[1];
  const float* bx  = (const float*)d_in[2];
  const float* Wh  = (const float*)d_in[3];
  const float* bh  = (const float*)d_in[4];
  const float* Wfc = (const float*)d_in[5];
  const float* bfc = (const float*)d_in[6];
  float* out = (float*)d_out;

  char* ws = (char*)d_ws;
  f16*   hbuf  = (f16*)ws;                 // 512KB chunk exchange
  float* hfin  = (float*)(ws + 524288);    // 512KB
  int*   flags = (int*)(ws + 1048576);     // 32KB

  hipMemsetAsync(flags, 0, 32768, stream); // stamps monotone within one run

  (void)hipFuncSetAttribute((const void*)rnn_core,
                            hipFuncAttributeMaxDynamicSharedMemorySize, LDS_SIZE);

  void* args[8];
  args[0] = (void*)&x;    args[1] = (void*)&Wx;   args[2] = (void*)&bx;
  args[3] = (void*)&Wh;   args[4] = (void*)&bh;   args[5] = (void*)&hbuf;
  args[6] = (void*)&hfin; args[7] = (void*)&flags;
  hipError_t err = hipLaunchCooperativeKernel((void*)rnn_core, dim3(256), dim3(256),
                                              args, LDS_SIZE, stream);
  if (err != hipSuccess) {
    rnn_core<<<dim3(256), dim3(256), LDS_SIZE, stream>>>(x, Wx, bx, Wh, bh, hbuf, hfin, flags);
  }

  fc_kernel<<<dim3(128), dim3(64), 0, stream>>>(hfin, Wfc, bfc, out);
}